// Round 13
// baseline (406.007 us; speedup 1.0000x reference)
//
#include <hip/hip_runtime.h>
#include <hip/hip_bf16.h>
#include <math.h>

#define L_TOK 43904          // 14*56*56 tokens
#define NWIN 128
#define NTOK 343
#define NHEAD 6
#define SCALE 0.17677669529663687f
#define LOG2E 1.4426950408889634f
#define NMASK -144.26950408889634f   // -100 * log2(e)
#define BSTRIDE 352                  // bias row stride (k padded, pad = -30000)
#define FIXMAX 16.0f                 // fixed softmax max (folded into biasC)

typedef __attribute__((ext_vector_type(8))) short short8;
typedef __attribute__((ext_vector_type(4))) float f32x4;

__device__ __forceinline__ unsigned short f2bf(float x) {
    union { float f; unsigned int u; } v; v.f = x;
    unsigned int r = v.u + 0x7fffu + ((v.u >> 16) & 1u);
    return (unsigned short)(r >> 16);
}
__device__ __forceinline__ unsigned int cvtpk(float a, float b) {
    unsigned int r;
    asm volatile("v_cvt_pk_bf16_f32 %0, %1, %2" : "=v"(r) : "v"(a), "v"(b));
    return r;
}
__device__ __forceinline__ void gload16(const void* g, void* l) {
    __builtin_amdgcn_global_load_lds((const __attribute__((address_space(1))) void*)g,
                                     (__attribute__((address_space(3))) void*)l, 16, 0, 0);
}

// map spatial token index l -> window-order row (roll -3 fused)
__device__ __forceinline__ int winrow(int l) {
    int s = l / 3136;
    int rem = l - s * 3136;
    int h = rem / 56;
    int w = rem - h * 56;
    int ps = s + 11; if (ps >= 14) ps -= 14;
    int ph = h + 53; if (ph >= 56) ph -= 56;
    int pw = w + 53; if (pw >= 56) pw -= 56;
    int wi = ((ps / 7) * 8 + ph / 7) * 8 + pw / 7;
    int tk = ((ps % 7) * 7 + ph % 7) * 7 + pw % 7;
    return wi * NTOK + tk;
}

// ---------------- weight conversion: f32 [K][N] -> bf16 [N][K]; q-scale*log2e folded ----------------
__global__ __launch_bounds__(256) void convert_weights(
    const float* __restrict__ qkv_w, const float* __restrict__ qkv_b,
    const float* __restrict__ proj_w, const float* __restrict__ fc1_w,
    const float* __restrict__ fc2_w,
    unsigned short* __restrict__ qkvT, unsigned short* __restrict__ projT,
    unsigned short* __restrict__ fc1T, unsigned short* __restrict__ fc2T,
    float* __restrict__ qkvb_s) {
    int stride = gridDim.x * 256;
    int t0 = blockIdx.x * 256 + threadIdx.x;
    const float qs = SCALE * LOG2E;
    for (int i = t0; i < 576 * 192; i += stride) {
        int n = i / 192, k = i - n * 192;
        float v = qkv_w[k * 576 + n];
        if (n < 192) v *= qs;
        qkvT[i] = f2bf(v);
    }
    for (int i = t0; i < 192 * 192; i += stride) {
        int n = i / 192, k = i - n * 192;
        projT[i] = f2bf(proj_w[k * 192 + n]);
    }
    for (int i = t0; i < 768 * 192; i += stride) {
        int n = i / 192, k = i - n * 192;
        fc1T[i] = f2bf(fc1_w[k * 768 + n]);
    }
    for (int i = t0; i < 192 * 768; i += stride) {
        int n = i / 768, k = i - n * 768;
        fc2T[i] = f2bf(fc2_w[k * 192 + n]);
    }
    for (int i = t0; i < 576; i += stride) {
        float v = qkv_b[i]; if (i < 192) v *= qs;
        qkvb_s[i] = v;
    }
}

// ---------------- compact rel-pos bias: biasC[h][q][352] f32, log2e folded, FIXMAX folded ----------------
__global__ __launch_bounds__(256) void bias_compact(const float* __restrict__ table, float* __restrict__ biasC) {
    int q = blockIdx.x;          // 0..342
    int qs = q / 49, qh = (q / 7) % 7, qw = q % 7;
    for (int k = threadIdx.x; k < BSTRIDE; k += 256) {
        if (k < NTOK) {
            int ks = k / 49, kh = (k / 7) % 7, kw = k % 7;
            int idx = ((qs - ks + 6) * 13 + (qh - kh + 6)) * 13 + (qw - kw + 6);
            #pragma unroll
            for (int h = 0; h < NHEAD; ++h)
                biasC[((size_t)h * NTOK + q) * BSTRIDE + k] = table[idx * 6 + h] * LOG2E - FIXMAX;
        } else {
            #pragma unroll
            for (int h = 0; h < NHEAD; ++h)
                biasC[((size_t)h * NTOK + q) * BSTRIDE + k] = -30000.f;
        }
    }
}

// ---------------- K1: transpose to (L,C) + LN1 + shifted window partition (bf16 out) ----------------
__global__ __launch_bounds__(256) void ln1_part(const float* __restrict__ x,
                                                const float* __restrict__ g, const float* __restrict__ b,
                                                float* __restrict__ xt, unsigned short* __restrict__ xw) {
    __shared__ float tile[192 * 65];
    __shared__ float red[4][64];
    __shared__ float red2[4][64];
    __shared__ float mu_s[64], rs_s[64];
    int l0 = blockIdx.x * 64;
    int tid = threadIdx.x;
    int j = tid & 63, c4 = tid >> 6;
    for (int cb = 0; cb < 192; cb += 4)
        tile[(cb + c4) * 65 + j] = x[(size_t)(cb + c4) * L_TOK + l0 + j];
    __syncthreads();
    float s = 0.f, ss = 0.f;
    for (int c = c4 * 48; c < c4 * 48 + 48; ++c) {
        float v = tile[c * 65 + j];
        s += v; ss += v * v;
    }
    red[c4][j] = s; red2[c4][j] = ss;
    __syncthreads();
    if (tid < 64) {
        float S = red[0][j] + red[1][j] + red[2][j] + red[3][j];
        float SS = red2[0][j] + red2[1][j] + red2[2][j] + red2[3][j];
        float mu = S * (1.f / 192.f);
        float var = SS * (1.f / 192.f) - mu * mu;
        mu_s[j] = mu;
        rs_s[j] = rsqrtf(var + 1e-5f);
    }
    __syncthreads();
    int wave = tid >> 6, lid = tid & 63;
    for (int t = wave; t < 64; t += 4) {
        int l = l0 + t;
        int r = winrow(l);
        float mu = mu_s[t], rs = rs_s[t];
        #pragma unroll
        for (int q = 0; q < 3; ++q) {
            int c = q * 64 + lid;
            float v = tile[c * 65 + t];
            xt[(size_t)l * 192 + c] = v;
            xw[(size_t)r * 192 + c] = f2bf((v - mu) * rs * g[c] + b[c]);
        }
    }
}

// ---------------- bf16 MFMA GEMM (QKV): C[M,N]=A[M,K]@Bt[N,K]^T + bias -> bf16 ----------------
__global__ __launch_bounds__(256, 3) void gemm_bf16(
    const unsigned short* __restrict__ A, const unsigned short* __restrict__ Bt,
    const float* __restrict__ bias, unsigned short* __restrict__ Cout, int N, int K) {
    __shared__ unsigned char smem[49152];
    unsigned short* sh = (unsigned short*)smem;
    const int tid = threadIdx.x;
    const int m0 = blockIdx.y * 128;
    const int n0 = blockIdx.x * 64;
    const int lane = tid & 63, wv = tid >> 6;
    const int wm = wv >> 1, wn = wv & 1;
    const int lr = lane & 15, lg = lane >> 4;
    const int KT = K >> 6;

    f32x4 acc[4][2];
    #pragma unroll
    for (int i = 0; i < 4; ++i)
        #pragma unroll
        for (int jj = 0; jj < 2; ++jj)
            acc[i][jj] = (f32x4){0.f, 0.f, 0.f, 0.f};

    #define STAGE(BUF, K0) { \
        unsigned short* dst = sh + (BUF) * 12288; \
        _Pragma("unroll") \
        for (int i_ = 0; i_ < 4; ++i_) { \
            int g_ = (i_ * 4 + wv) * 64 + lane; \
            int row_ = g_ >> 3, gc_ = g_ & 7; \
            gload16(A + (size_t)(m0 + row_) * K + (K0) + ((gc_ ^ (row_ & 7)) << 3), dst + g_ * 8); \
        } \
        _Pragma("unroll") \
        for (int i_ = 0; i_ < 2; ++i_) { \
            int g_ = (i_ * 4 + wv) * 64 + lane; \
            int row_ = g_ >> 3, gc_ = g_ & 7; \
            gload16(Bt + (size_t)(n0 + row_) * K + (K0) + ((gc_ ^ (row_ & 7)) << 3), dst + 8192 + g_ * 8); \
        } }

    STAGE(0, 0);
    __syncthreads();
    for (int kt = 0; kt < KT; ++kt) {
        int buf = kt & 1;
        if (kt + 1 < KT) STAGE(buf ^ 1, (kt + 1) << 6);
        const unsigned short* sA = sh + buf * 12288;
        const unsigned short* sB = sA + 8192;
        #pragma unroll
        for (int kk = 0; kk < 2; ++kk) {
            short8 a[4], b[2];
            #pragma unroll
            for (int i = 0; i < 4; ++i) {
                int row = wm * 64 + i * 16 + lr;
                a[i] = *(const short8*)(sA + row * 64 + (((kk * 4 + lg) ^ (lr & 7)) << 3));
            }
            #pragma unroll
            for (int jj = 0; jj < 2; ++jj) {
                int row = wn * 32 + jj * 16 + lr;
                b[jj] = *(const short8*)(sB + row * 64 + (((kk * 4 + lg) ^ (lr & 7)) << 3));
            }
            #pragma unroll
            for (int i = 0; i < 4; ++i)
                #pragma unroll
                for (int jj = 0; jj < 2; ++jj)
                    acc[i][jj] = __builtin_amdgcn_mfma_f32_16x16x32_bf16(a[i], b[jj], acc[i][jj], 0, 0, 0);
        }
        __syncthreads();
    }
    #undef STAGE

    float bia[2];
    bia[0] = bias[n0 + wn * 32 + lr];
    bia[1] = bias[n0 + wn * 32 + 16 + lr];
    #pragma unroll
    for (int i = 0; i < 4; ++i) {
        #pragma unroll
        for (int jj = 0; jj < 2; ++jj) {
            #pragma unroll
            for (int r = 0; r < 4; ++r) {
                int row = m0 + wm * 64 + i * 16 + lg * 4 + r;
                int col = n0 + wn * 32 + jj * 16 + lr;
                Cout[(size_t)row * N + col] = f2bf(acc[i][jj][r] + bia[jj]);
            }
        }
    }
}

// ---------------- fused proj GEMM + window-reverse residual + LN2 ----------------
__global__ __launch_bounds__(256) void gemm_proj_ln(
    const unsigned short* __restrict__ A, const unsigned short* __restrict__ Bt,
    const float* __restrict__ bias, const float* __restrict__ g2, const float* __restrict__ b2,
    float* __restrict__ xt, unsigned short* __restrict__ h1) {
    __shared__ unsigned short As[2][64 * 64];
    __shared__ unsigned short Bs[2][192 * 64];
    const int tid = threadIdx.x;
    const int m0 = blockIdx.x * 64;
    const int lane = tid & 63, wv = tid >> 6;
    const int lr = lane & 15, lg = lane >> 4;
    const int K = 192;

    f32x4 acc[12];
    #pragma unroll
    for (int jj = 0; jj < 12; ++jj) acc[jj] = (f32x4){0.f, 0.f, 0.f, 0.f};

    #define PSTAGE(BUF, K0) { \
        _Pragma("unroll") \
        for (int i_ = 0; i_ < 2; ++i_) { \
            int g_ = i_ * 256 + tid; \
            int row_ = g_ >> 3, gc_ = g_ & 7; \
            gload16(A + (size_t)(m0 + row_) * K + (K0) + ((gc_ ^ (row_ & 7)) << 3), &As[BUF][g_ * 8]); \
        } \
        _Pragma("unroll") \
        for (int i_ = 0; i_ < 6; ++i_) { \
            int g_ = i_ * 256 + tid; \
            int row_ = g_ >> 3, gc_ = g_ & 7; \
            gload16(Bt + (size_t)row_ * K + (K0) + ((gc_ ^ (row_ & 7)) << 3), &Bs[BUF][g_ * 8]); \
        } }

    PSTAGE(0, 0);
    __syncthreads();
    for (int kt = 0; kt < 3; ++kt) {
        int buf = kt & 1;
        if (kt + 1 < 3) PSTAGE(buf ^ 1, (kt + 1) << 6);
        #pragma unroll
        for (int kk = 0; kk < 2; ++kk) {
            int arow = wv * 16 + lr;
            short8 a = *(const short8*)(&As[buf][arow * 64 + (((kk * 4 + lg) ^ (lr & 7)) << 3)]);
            #pragma unroll
            for (int jj = 0; jj < 12; ++jj) {
                int brow = jj * 16 + lr;
                short8 b = *(const short8*)(&Bs[buf][brow * 64 + (((kk * 4 + lg) ^ (lr & 7)) << 3)]);
                acc[jj] = __builtin_amdgcn_mfma_f32_16x16x32_bf16(a, b, acc[jj], 0, 0, 0);
            }
        }
        __syncthreads();
    }
    #undef PSTAGE

    #pragma unroll
    for (int r = 0; r < 4; ++r) {
        int m = m0 + wv * 16 + lg * 4 + r;      // window-order row
        int wi = m / 343, tk = m - wi * 343;
        int ts = tk / 49, rm = tk - ts * 49, th = rm / 7, tw = rm - th * 7;
        int ps = (wi >> 6) * 7 + ts, ph = ((wi >> 3) & 7) * 7 + th, pw = (wi & 7) * 7 + tw;
        int ss_ = ps + 3; if (ss_ >= 14) ss_ -= 14;
        int hh = ph + 3; if (hh >= 56) hh -= 56;
        int ww = pw + 3; if (ww >= 56) ww -= 56;
        size_t l = ((size_t)ss_ * 56 + hh) * 56 + ww;
        float val[12];
        float sum = 0.f, ssum = 0.f;
        #pragma unroll
        for (int jj = 0; jj < 12; ++jj) {
            int col = jj * 16 + lr;
            float v = acc[jj][r] + bias[col] + xt[l * 192 + col];
            xt[l * 192 + col] = v;
            val[jj] = v; sum += v; ssum += v * v;
        }
        #pragma unroll
        for (int off = 1; off < 16; off <<= 1) {
            sum += __shfl_xor(sum, off);
            ssum += __shfl_xor(ssum, off);
        }
        float mu = sum * (1.f / 192.f);
        float rs = rsqrtf(ssum * (1.f / 192.f) - mu * mu + 1e-5f);
        #pragma unroll
        for (int jj = 0; jj < 12; ++jj) {
            int col = jj * 16 + lr;
            h1[l * 192 + col] = f2bf((val[jj] - mu) * rs * g2[col] + b2[col]);
        }
    }
}

// ---------------- fused MLP: h1 -> fc1+GELU -> fc2 + xt residual -> transposed out (C,L) ----------------
// R11 retry: explicit __syncthreads() around the h_s LDS bounce (cross-lane RAW the compiler's
// alias analysis cannot see -> R11's replay divergence). Each wave reads only its own h_s[wv];
// the barriers just force LDS write completion + block reordering.
__global__ __launch_bounds__(256) void mlp_fused(
    const unsigned short* __restrict__ A,      // h1 [L][192] bf16
    const unsigned short* __restrict__ W1,     // fc1T [768][192] bf16
    const float* __restrict__ b1,
    const unsigned short* __restrict__ W2,     // fc2T [192][768] bf16
    const float* __restrict__ b2,
    const float* __restrict__ xt,
    float* __restrict__ out) {
    __shared__ unsigned short A_s[64 * 192];   // 24KB; aliased as Cs f32[64][68] in epilogue
    __shared__ unsigned short h_s[4][16][72];  // per-wave hidden bounce, padded
    const int tid = threadIdx.x;
    const int m0 = blockIdx.x * 64;
    const int lane = tid & 63, wv = tid >> 6;
    const int lr = lane & 15, lg = lane >> 4;

    // stage A tile (64 x 192), source pre-swizzled chunks (8 elem) within each row
    #pragma unroll
    for (int i = 0; i < 6; ++i) {
        int g = i * 256 + tid;
        int row = g / 24, gc = g - row * 24;
        gload16(A + (size_t)(m0 + row) * 192 + ((gc ^ (row & 7)) << 3), A_s + g * 8);
    }
    __syncthreads();

    f32x4 acc2[12];
    #pragma unroll
    for (int j = 0; j < 12; ++j) acc2[j] = (f32x4){0.f, 0.f, 0.f, 0.f};

    const unsigned short* Arow = A_s + (wv * 16 + lr) * 192;
    const int asw = lr & 7;   // (wv*16+lr)&7 == lr&7

    #pragma unroll 1
    for (int hc = 0; hc < 12; ++hc) {
        // fc1: 16 tokens x 64 hidden cols
        f32x4 acc1[4];
        #pragma unroll
        for (int j = 0; j < 4; ++j) acc1[j] = (f32x4){0.f, 0.f, 0.f, 0.f};
        #pragma unroll
        for (int kt = 0; kt < 6; ++kt) {
            short8 a = *(const short8*)(Arow + (((kt * 4 + lg) ^ asw) << 3));
            #pragma unroll
            for (int jj = 0; jj < 4; ++jj) {
                short8 b = *(const short8*)(W1 + (size_t)(hc * 64 + jj * 16 + lr) * 192 + kt * 32 + lg * 8);
                acc1[jj] = __builtin_amdgcn_mfma_f32_16x16x32_bf16(a, b, acc1[jj], 0, 0, 0);
            }
        }
        // bias + exact GELU -> per-wave LDS bounce (C-frag: token=lg*4+r, hid=jj*16+lr)
        #pragma unroll
        for (int jj = 0; jj < 4; ++jj) {
            float bb = b1[hc * 64 + jj * 16 + lr];
            #pragma unroll
            for (int r = 0; r < 4; ++r) {
                float v = acc1[jj][r] + bb;
                v = 0.5f * v * (1.f + erff(v * 0.70710678118654752f));
                h_s[wv][lg * 4 + r][jj * 16 + lr] = f2bf(v);
            }
        }
        __syncthreads();   // h_s writes visible/complete before reads (cross-lane RAW)
        // fc2 accumulate over this hidden chunk (K=64 -> 2 k-steps)
        #pragma unroll
        for (int k0 = 0; k0 < 2; ++k0) {
            short8 hf = *(const short8*)(&h_s[wv][lr][k0 * 32 + lg * 8]);
            #pragma unroll
            for (int j2 = 0; j2 < 12; ++j2) {
                short8 b = *(const short8*)(W2 + (size_t)(j2 * 16 + lr) * 768 + hc * 64 + k0 * 32 + lg * 8);
                acc2[j2] = __builtin_amdgcn_mfma_f32_16x16x32_bf16(hf, b, acc2[j2], 0, 0, 0);
            }
        }
        __syncthreads();   // fc2 reads complete before next iteration's h_s overwrite
    }

    // epilogue: + b2 + xt residual, transpose via LDS (aliasing A_s), write out (C,L)
    float* Cs = (float*)A_s;   // [64][68] f32 = 17.4KB < 24KB; A_s dead after last barrier
    #pragma unroll
    for (int g = 0; g < 3; ++g) {
        #pragma unroll
        for (int jq = 0; jq < 4; ++jq) {
            int j2 = g * 4 + jq;
            int col = j2 * 16 + lr;
            #pragma unroll
            for (int r = 0; r < 4; ++r) {
                int row = wv * 16 + lg * 4 + r;
                float v = acc2[j2][r] + b2[col] + xt[(size_t)(m0 + row) * 192 + col];
                Cs[row * 68 + jq * 16 + lr] = v;
            }
        }
        __syncthreads();
        int cl = tid & 63;
        #pragma unroll
        for (int j4 = tid >> 6; j4 < 16; j4 += 4) {
            f32x4 v;
            #pragma unroll
            for (int t = 0; t < 4; ++t) v[t] = Cs[(j4 * 4 + t) * 68 + cl];
            *(f32x4*)&out[(size_t)(g * 64 + cl) * L_TOK + m0 + j4 * 4] = v;
        }
        __syncthreads();
    }
}

// ---------------- flash attention, fixed-max softmax (R10 proven form: scalar lsum) ----------------
__global__ __launch_bounds__(256) void attn_flash(
    const unsigned short* __restrict__ qkv, const float* __restrict__ biasC,
    unsigned short* __restrict__ aout) {
    __shared__ unsigned short Ks[352 * 32];     // K rows, chunk-swizzled
    __shared__ unsigned short Vt[32][360];      // V transposed [dim][key]
    __shared__ unsigned int Ps2[4][16][20];     // per-wave P repack scratch
    __shared__ unsigned char regq[352];
    const int w = blockIdx.x, h = blockIdx.y;
    const int tid = threadIdx.x;
    const size_t base = (size_t)w * NTOK * 576;

    for (int g = tid; g < 1372; g += 256) {
        int row = g >> 2, c = g & 3;
        gload16(qkv + base + (size_t)row * 576 + 192 + h * 32 + ((c ^ ((row >> 1) & 3)) << 3), Ks + g * 8);
    }
    if (tid < 36) {
        short8 z = {};
        *(short8*)(Ks + (343 + (tid >> 2)) * 32 + (tid & 3) * 8) = z;
    }
    for (int idx = tid; idx < 688; idx += 256) {
        int jp = idx >> 2, c = idx & 3;
        int j0 = jp * 2, j1 = j0 + 1;
        short8 v0 = *(const short8*)(qkv + base + (size_t)j0 * 576 + 384 + h * 32 + c * 8);
        short8 v1 = {};
        if (j1 < NTOK) v1 = *(const short8*)(qkv + base + (size_t)j1 * 576 + 384 + h * 32 + c * 8);
        #pragma unroll
        for (int i = 0; i < 8; ++i) {
            ushort2 pr; pr.x = (unsigned short)v0[i]; pr.y = (unsigned short)v1[i];
            *(ushort2*)&Vt[c * 8 + i][j0] = pr;
        }
    }
    for (int idx = tid; idx < 128; idx += 256) {
        ushort2 z; z.x = 0; z.y = 0;
        *(ushort2*)&Vt[idx >> 2][344 + (idx & 3) * 2] = z;
    }
    {
        const int wis = w >> 6, wih = (w >> 3) & 7, wiw = w & 7;
        for (int n = tid; n < 352; n += 256) {
            unsigned char rv = 0;
            if (n < NTOK) {
                int ts = n / 49, r49 = n - ts * 49, th = r49 / 7, tw = r49 - th * 7;
                int ps = wis * 7 + ts, ph = wih * 7 + th, pw = wiw * 7 + tw;
                int rs = ps < 7 ? 0 : (ps < 11 ? 1 : 2);
                int rh = ph < 49 ? 0 : (ph < 53 ? 1 : 2);
                int rw = pw < 49 ? 0 : (pw < 53 ? 1 : 2);
                rv = (unsigned char)(rs * 9 + rh * 3 + rw);
            }
            regq[n] = rv;
        }
    }
    __syncthreads();

    const int wid = tid >> 6, l = tid & 63, lr = l & 15, lg = l >> 4;
    const int kchunk = (lg ^ ((lr >> 1) & 3)) << 3;   // swizzled Ks read offset

    for (int qt = wid; qt < 22; qt += 4) {
        int qrow = qt * 16 + lr;
        int qr = qrow < NTOK ? qrow : NTOK - 1;
        short8 qa = *(const short8*)(qkv + base + (size_t)qr * 576 + h * 32 + lg * 8);
        unsigned int rq = regq[qr];
        const float* bq = biasC + ((size_t)h * NTOK + qr) * BSTRIDE + lg * 4;

        float lsum = 0.f;
        f32x4 o0 = (f32x4){0.f, 0.f, 0.f, 0.f};
        f32x4 o1 = (f32x4){0.f, 0.f, 0.f, 0.f};
        const f32x4 zv = (f32x4){0.f, 0.f, 0.f, 0.f};

        #pragma unroll 1
        for (int kb = 0; kb < 11; ++kb) {
            const int kt0 = 2 * kb, kt1 = 2 * kb + 1;
            short8 k0 = *(const short8*)(Ks + (kt0 * 16 + lr) * 32 + kchunk);
            short8 k1 = *(const short8*)(Ks + (kt1 * 16 + lr) * 32 + kchunk);
            f32x4 s0 = __builtin_amdgcn_mfma_f32_16x16x32_bf16(k0, qa, zv, 0, 0, 0);
            f32x4 s1 = __builtin_amdgcn_mfma_f32_16x16x32_bf16(k1, qa, zv, 0, 0, 0);
            f32x4 bv0 = *(const f32x4*)(bq + kt0 * 16);
            f32x4 bv1 = *(const f32x4*)(bq + kt1 * 16);
            unsigned int rb0 = *(const unsigned int*)&regq[kt0 * 16 + lg * 4];
            unsigned int rb1 = *(const unsigned int*)&regq[kt1 * 16 + lg * 4];
            f32x4 p0, p1;
            #pragma unroll
            for (int r = 0; r < 4; ++r) {
                float m0 = (((rb0 >> (r * 8)) & 255u) != rq) ? NMASK : 0.f;
                float m1 = (((rb1 >> (r * 8)) & 255u) != rq) ? NMASK : 0.f;
                p0[r] = exp2f(s0[r] + bv0[r] + m0);
                p1[r] = exp2f(s1[r] + bv1[r] + m1);
                lsum += p0[r] + p1[r];
            }
            Ps2[wid][lr][lg * 2 + 0] = cvtpk(p0[0], p0[1]);
            Ps2[wid][lr][lg * 2 + 1] = cvtpk(p0[2], p0[3]);
            Ps2[wid][lr][8 + lg * 2 + 0] = cvtpk(p1[0], p1[1]);
            Ps2[wid][lr][8 + lg * 2 + 1] = cvtpk(p1[2], p1[3]);
            short8 pa = *(const short8*)&Ps2[wid][lr][lg * 4];
            short8 v0 = *(const short8*)&Vt[lr][kb * 32 + lg * 8];
            short8 v1 = *(const short8*)&Vt[16 + lr][kb * 32 + lg * 8];
            o0 = __builtin_amdgcn_mfma_f32_16x16x32_bf16(pa, v0, o0, 0, 0, 0);
            o1 = __builtin_amdgcn_mfma_f32_16x16x32_bf16(pa, v1, o1, 0, 0, 0);
        }
        lsum += __shfl_xor(lsum, 16);
        lsum += __shfl_xor(lsum, 32);
        float inv = 1.f / lsum;

        #pragma unroll
        for (int r = 0; r < 4; ++r) {
            float iv = __shfl(inv, lg * 4 + r);
            int q = qt * 16 + lg * 4 + r;
            if (q < NTOK) {
                size_t orow = ((size_t)w * NTOK + q) * 192 + h * 32;
                aout[orow + lr] = f2bf(o0[r] * iv);
                aout[orow + 16 + lr] = f2bf(o1[r] * iv);
            }
        }
    }
}

extern "C" void kernel_launch(void* const* d_in, const int* in_sizes, int n_in,
                              void* d_out, int out_size, void* d_ws, size_t ws_size,
                              hipStream_t stream) {
    const float* x      = (const float*)d_in[0];
    const float* n1g    = (const float*)d_in[1];
    const float* n1b    = (const float*)d_in[2];
    const float* qkv_w  = (const float*)d_in[3];
    const float* qkv_b  = (const float*)d_in[4];
    const float* rpb    = (const float*)d_in[5];
    const float* proj_w = (const float*)d_in[6];
    const float* proj_b = (const float*)d_in[7];
    const float* n2g    = (const float*)d_in[8];
    const float* n2b    = (const float*)d_in[9];
    const float* fc1_w  = (const float*)d_in[10];
    const float* fc1_b  = (const float*)d_in[11];
    const float* fc2_w  = (const float*)d_in[12];
    const float* fc2_b  = (const float*)d_in[13];
    float* out = (float*)d_out;

    // workspace layout (R12 layout kept; h2 region now unused)
    char* p = (char*)d_ws;
    float* xt = (float*)p;                     p += (size_t)L_TOK * 192 * 4;   // residual f32
    unsigned short* xw = (unsigned short*)p;   // LN1 out bf16; later h1 (LN2 out bf16)
    unsigned short* h1 = xw;                   p += (size_t)L_TOK * 192 * 2;
    unsigned short* qkvb = (unsigned short*)p; p += (size_t)L_TOK * 768 * 2;   // qkv bf16 [L][576]
    unsigned short* aoutb = (unsigned short*)p; p += (size_t)L_TOK * 192 * 2;  // attn out bf16
    float* biasC = (float*)p;                  p += (size_t)NHEAD * NTOK * BSTRIDE * 4 + 256;
    unsigned short* qkvT = (unsigned short*)p; p += (size_t)576 * 192 * 2;
    unsigned short* projT = (unsigned short*)p; p += (size_t)192 * 192 * 2;
    unsigned short* fc1T = (unsigned short*)p; p += (size_t)768 * 192 * 2;
    unsigned short* fc2T = (unsigned short*)p; p += (size_t)192 * 768 * 2;
    float* qkvb_s = (float*)p;                 p += 576 * 4;

    convert_weights<<<576, 256, 0, stream>>>(qkv_w, qkv_b, proj_w, fc1_w, fc2_w,
                                             qkvT, projT, fc1T, fc2T, qkvb_s);
    bias_compact<<<343, 256, 0, stream>>>(rpb, biasC);
    ln1_part<<<686, 256, 0, stream>>>(x, n1g, n1b, xt, xw);
    // QKV: (L,192)@(192,576) -> bf16 (q pre-scaled). Grid (n, m) for A-panel L2 reuse.
    gemm_bf16<<<dim3(9, 343), 256, 0, stream>>>(xw, qkvT, qkvb_s, qkvb, 576, 192);
    // attention -> aoutb bf16
    attn_flash<<<dim3(NWIN, NHEAD), 256, 0, stream>>>(qkvb, biasC, aoutb);
    // fused proj + window-reverse residual (xt inout) + LN2 -> h1 bf16
    gemm_proj_ln<<<686, 256, 0, stream>>>(aoutb, projT, proj_b, n2g, n2b, xt, h1);
    // fused MLP: fc1+GELU+fc2 + xt residual -> transposed out (C,L)
    mlp_fused<<<686, 256, 0, stream>>>(h1, fc1T, fc1_b, fc2T, fc2_b, xt, out);
}

// Round 14
// 223.720 us; speedup vs baseline: 1.8148x; 1.8148x over previous
//
#include <hip/hip_runtime.h>
#include <hip/hip_bf16.h>
#include <math.h>

#define L_TOK 43904          // 14*56*56 tokens
#define NWIN 128
#define NTOK 343
#define NHEAD 6
#define SCALE 0.17677669529663687f
#define LOG2E 1.4426950408889634f
#define NMASK -144.26950408889634f   // -100 * log2(e)
#define BSTRIDE 352                  // bias row stride (k padded, pad = -30000)
#define FIXMAX 16.0f                 // fixed softmax max (folded into biasC)

typedef __attribute__((ext_vector_type(8))) short short8;
typedef __attribute__((ext_vector_type(4))) float f32x4;

__device__ __forceinline__ unsigned short f2bf(float x) {
    union { float f; unsigned int u; } v; v.f = x;
    unsigned int r = v.u + 0x7fffu + ((v.u >> 16) & 1u);
    return (unsigned short)(r >> 16);
}
__device__ __forceinline__ unsigned int cvtpk(float a, float b) {
    unsigned int r;
    asm volatile("v_cvt_pk_bf16_f32 %0, %1, %2" : "=v"(r) : "v"(a), "v"(b));
    return r;
}
__device__ __forceinline__ void gload16(const void* g, void* l) {
    __builtin_amdgcn_global_load_lds((const __attribute__((address_space(1))) void*)g,
                                     (__attribute__((address_space(3))) void*)l, 16, 0, 0);
}

// map spatial token index l -> window-order row (roll -3 fused)
__device__ __forceinline__ int winrow(int l) {
    int s = l / 3136;
    int rem = l - s * 3136;
    int h = rem / 56;
    int w = rem - h * 56;
    int ps = s + 11; if (ps >= 14) ps -= 14;
    int ph = h + 53; if (ph >= 56) ph -= 56;
    int pw = w + 53; if (pw >= 56) pw -= 56;
    int wi = ((ps / 7) * 8 + ph / 7) * 8 + pw / 7;
    int tk = ((ps % 7) * 7 + ph % 7) * 7 + pw % 7;
    return wi * NTOK + tk;
}

// ---------------- merged prep: weight conversion (blocks 0..575) + bias table (blocks 576..918) ----------------
__global__ __launch_bounds__(256) void prep_kernel(
    const float* __restrict__ qkv_w, const float* __restrict__ qkv_b,
    const float* __restrict__ proj_w, const float* __restrict__ fc1_w,
    const float* __restrict__ fc2_w, const float* __restrict__ table,
    unsigned short* __restrict__ qkvT, unsigned short* __restrict__ projT,
    unsigned short* __restrict__ fc1T, unsigned short* __restrict__ fc2T,
    float* __restrict__ qkvb_s, float* __restrict__ biasC) {
    const float qs = SCALE * LOG2E;
    if (blockIdx.x < 576) {
        int stride = 576 * 256;
        int t0 = blockIdx.x * 256 + threadIdx.x;
        for (int i = t0; i < 576 * 192; i += stride) {
            int n = i / 192, k = i - n * 192;
            float v = qkv_w[k * 576 + n];
            if (n < 192) v *= qs;
            qkvT[i] = f2bf(v);
        }
        for (int i = t0; i < 192 * 192; i += stride) {
            int n = i / 192, k = i - n * 192;
            projT[i] = f2bf(proj_w[k * 192 + n]);
        }
        for (int i = t0; i < 768 * 192; i += stride) {
            int n = i / 192, k = i - n * 192;
            fc1T[i] = f2bf(fc1_w[k * 768 + n]);
        }
        for (int i = t0; i < 192 * 768; i += stride) {
            int n = i / 768, k = i - n * 768;
            fc2T[i] = f2bf(fc2_w[k * 192 + n]);
        }
        for (int i = t0; i < 576; i += stride) {
            float v = qkv_b[i]; if (i < 192) v *= qs;
            qkvb_s[i] = v;
        }
    } else {
        int q = blockIdx.x - 576;      // 0..342
        int qs3 = q / 49, qh = (q / 7) % 7, qw = q % 7;
        for (int k = threadIdx.x; k < BSTRIDE; k += 256) {
            if (k < NTOK) {
                int ks = k / 49, kh = (k / 7) % 7, kw = k % 7;
                int idx = ((qs3 - ks + 6) * 13 + (qh - kh + 6)) * 13 + (qw - kw + 6);
                #pragma unroll
                for (int h = 0; h < NHEAD; ++h)
                    biasC[((size_t)h * NTOK + q) * BSTRIDE + k] = table[idx * 6 + h] * LOG2E - FIXMAX;
            } else {
                #pragma unroll
                for (int h = 0; h < NHEAD; ++h)
                    biasC[((size_t)h * NTOK + q) * BSTRIDE + k] = -30000.f;
            }
        }
    }
}

// ---------------- K1: transpose to (L,C) + LN1 + shifted window partition (bf16 out) ----------------
__global__ __launch_bounds__(256) void ln1_part(const float* __restrict__ x,
                                                const float* __restrict__ g, const float* __restrict__ b,
                                                float* __restrict__ xt, unsigned short* __restrict__ xw) {
    __shared__ float tile[192 * 65];
    __shared__ float red[4][64];
    __shared__ float red2[4][64];
    __shared__ float mu_s[64], rs_s[64];
    int l0 = blockIdx.x * 64;
    int tid = threadIdx.x;
    int j = tid & 63, c4 = tid >> 6;
    for (int cb = 0; cb < 192; cb += 4)
        tile[(cb + c4) * 65 + j] = x[(size_t)(cb + c4) * L_TOK + l0 + j];
    __syncthreads();
    float s = 0.f, ss = 0.f;
    for (int c = c4 * 48; c < c4 * 48 + 48; ++c) {
        float v = tile[c * 65 + j];
        s += v; ss += v * v;
    }
    red[c4][j] = s; red2[c4][j] = ss;
    __syncthreads();
    if (tid < 64) {
        float S = red[0][j] + red[1][j] + red[2][j] + red[3][j];
        float SS = red2[0][j] + red2[1][j] + red2[2][j] + red2[3][j];
        float mu = S * (1.f / 192.f);
        float var = SS * (1.f / 192.f) - mu * mu;
        mu_s[j] = mu;
        rs_s[j] = rsqrtf(var + 1e-5f);
    }
    __syncthreads();
    int wave = tid >> 6, lid = tid & 63;
    for (int t = wave; t < 64; t += 4) {
        int l = l0 + t;
        int r = winrow(l);
        float mu = mu_s[t], rs = rs_s[t];
        #pragma unroll
        for (int q = 0; q < 3; ++q) {
            int c = q * 64 + lid;
            float v = tile[c * 65 + t];
            xt[(size_t)l * 192 + c] = v;
            xw[(size_t)r * 192 + c] = f2bf((v - mu) * rs * g[c] + b[c]);
        }
    }
}

// ---------------- bf16 MFMA GEMM: C[M,N]=A[M,K]@Bt[N,K]^T + bias ----------------
// BM=128 BN=64 BK=64. Grid: (x = n-block, y = m-block) so consecutive blocks share the A panel (L2 reuse).
// EPI=1: exact GELU. OUTMODE: 0=bf16, 1=f32, 2=f32 transposed out[(n0+c)*L+m] with xt-residual add.
template<int EPI, int OUTMODE>
__global__ __launch_bounds__(256, 3) void gemm_bf16(
    const unsigned short* __restrict__ A, const unsigned short* __restrict__ Bt,
    const float* __restrict__ bias, void* __restrict__ Cout,
    const float* __restrict__ xt, int N, int K) {
    __shared__ unsigned char smem[49152];
    unsigned short* sh = (unsigned short*)smem;
    const int tid = threadIdx.x;
    const int m0 = blockIdx.y * 128;
    const int n0 = blockIdx.x * 64;
    const int lane = tid & 63, wv = tid >> 6;
    const int wm = wv >> 1, wn = wv & 1;
    const int lr = lane & 15, lg = lane >> 4;
    const int KT = K >> 6;

    f32x4 acc[4][2];
    #pragma unroll
    for (int i = 0; i < 4; ++i)
        #pragma unroll
        for (int jj = 0; jj < 2; ++jj)
            acc[i][jj] = (f32x4){0.f, 0.f, 0.f, 0.f};

    #define STAGE(BUF, K0) { \
        unsigned short* dst = sh + (BUF) * 12288; \
        _Pragma("unroll") \
        for (int i_ = 0; i_ < 4; ++i_) { \
            int g_ = (i_ * 4 + wv) * 64 + lane; \
            int row_ = g_ >> 3, gc_ = g_ & 7; \
            gload16(A + (size_t)(m0 + row_) * K + (K0) + ((gc_ ^ (row_ & 7)) << 3), dst + g_ * 8); \
        } \
        _Pragma("unroll") \
        for (int i_ = 0; i_ < 2; ++i_) { \
            int g_ = (i_ * 4 + wv) * 64 + lane; \
            int row_ = g_ >> 3, gc_ = g_ & 7; \
            gload16(Bt + (size_t)(n0 + row_) * K + (K0) + ((gc_ ^ (row_ & 7)) << 3), dst + 8192 + g_ * 8); \
        } }

    STAGE(0, 0);
    __syncthreads();
    for (int kt = 0; kt < KT; ++kt) {
        int buf = kt & 1;
        if (kt + 1 < KT) STAGE(buf ^ 1, (kt + 1) << 6);
        const unsigned short* sA = sh + buf * 12288;
        const unsigned short* sB = sA + 8192;
        #pragma unroll
        for (int kk = 0; kk < 2; ++kk) {
            short8 a[4], b[2];
            #pragma unroll
            for (int i = 0; i < 4; ++i) {
                int row = wm * 64 + i * 16 + lr;
                a[i] = *(const short8*)(sA + row * 64 + (((kk * 4 + lg) ^ (lr & 7)) << 3));
            }
            #pragma unroll
            for (int jj = 0; jj < 2; ++jj) {
                int row = wn * 32 + jj * 16 + lr;
                b[jj] = *(const short8*)(sB + row * 64 + (((kk * 4 + lg) ^ (lr & 7)) << 3));
            }
            #pragma unroll
            for (int i = 0; i < 4; ++i)
                #pragma unroll
                for (int jj = 0; jj < 2; ++jj)
                    acc[i][jj] = __builtin_amdgcn_mfma_f32_16x16x32_bf16(a[i], b[jj], acc[i][jj], 0, 0, 0);
        }
        __syncthreads();
    }
    #undef STAGE

    if (OUTMODE == 2) {
        float* Cs = (float*)smem;   // [128][68]
        #pragma unroll
        for (int i = 0; i < 4; ++i)
            #pragma unroll
            for (int jj = 0; jj < 2; ++jj)
                #pragma unroll
                for (int r = 0; r < 4; ++r) {
                    int row = wm * 64 + i * 16 + lg * 4 + r;
                    int col = wn * 32 + jj * 16 + lr;
                    float v = acc[i][jj][r] + bias[n0 + col] + xt[(size_t)(m0 + row) * 192 + n0 + col];
                    Cs[row * 68 + col] = v;
                }
        __syncthreads();
        float* outp = (float*)Cout;
        int c = tid & 63;
        #pragma unroll
        for (int j4 = tid >> 6; j4 < 32; j4 += 4) {
            f32x4 v;
            #pragma unroll
            for (int t = 0; t < 4; ++t) v[t] = Cs[(j4 * 4 + t) * 68 + c];
            *(f32x4*)&outp[(size_t)(n0 + c) * L_TOK + m0 + j4 * 4] = v;
        }
    } else {
        float bia[2];
        bia[0] = bias[n0 + wn * 32 + lr];
        bia[1] = bias[n0 + wn * 32 + 16 + lr];
        #pragma unroll
        for (int i = 0; i < 4; ++i) {
            #pragma unroll
            for (int jj = 0; jj < 2; ++jj) {
                #pragma unroll
                for (int r = 0; r < 4; ++r) {
                    float v = acc[i][jj][r] + bia[jj];
                    if (EPI == 1) v = 0.5f * v * (1.f + erff(v * 0.70710678118654752f));
                    int row = m0 + wm * 64 + i * 16 + lg * 4 + r;
                    int col = n0 + wn * 32 + jj * 16 + lr;
                    if (OUTMODE == 1) ((float*)Cout)[(size_t)row * N + col] = v;
                    else ((unsigned short*)Cout)[(size_t)row * N + col] = f2bf(v);
                }
            }
        }
    }
}

// ---------------- fused proj GEMM + window-reverse residual + LN2 ----------------
__global__ __launch_bounds__(256) void gemm_proj_ln(
    const unsigned short* __restrict__ A, const unsigned short* __restrict__ Bt,
    const float* __restrict__ bias, const float* __restrict__ g2, const float* __restrict__ b2,
    float* __restrict__ xt, unsigned short* __restrict__ h1) {
    __shared__ unsigned short As[2][64 * 64];
    __shared__ unsigned short Bs[2][192 * 64];
    const int tid = threadIdx.x;
    const int m0 = blockIdx.x * 64;
    const int lane = tid & 63, wv = tid >> 6;
    const int lr = lane & 15, lg = lane >> 4;
    const int K = 192;

    f32x4 acc[12];
    #pragma unroll
    for (int jj = 0; jj < 12; ++jj) acc[jj] = (f32x4){0.f, 0.f, 0.f, 0.f};

    #define PSTAGE(BUF, K0) { \
        _Pragma("unroll") \
        for (int i_ = 0; i_ < 2; ++i_) { \
            int g_ = i_ * 256 + tid; \
            int row_ = g_ >> 3, gc_ = g_ & 7; \
            gload16(A + (size_t)(m0 + row_) * K + (K0) + ((gc_ ^ (row_ & 7)) << 3), &As[BUF][g_ * 8]); \
        } \
        _Pragma("unroll") \
        for (int i_ = 0; i_ < 6; ++i_) { \
            int g_ = i_ * 256 + tid; \
            int row_ = g_ >> 3, gc_ = g_ & 7; \
            gload16(Bt + (size_t)row_ * K + (K0) + ((gc_ ^ (row_ & 7)) << 3), &Bs[BUF][g_ * 8]); \
        } }

    PSTAGE(0, 0);
    __syncthreads();
    for (int kt = 0; kt < 3; ++kt) {
        int buf = kt & 1;
        if (kt + 1 < 3) PSTAGE(buf ^ 1, (kt + 1) << 6);
        #pragma unroll
        for (int kk = 0; kk < 2; ++kk) {
            int arow = wv * 16 + lr;
            short8 a = *(const short8*)(&As[buf][arow * 64 + (((kk * 4 + lg) ^ (lr & 7)) << 3)]);
            #pragma unroll
            for (int jj = 0; jj < 12; ++jj) {
                int brow = jj * 16 + lr;
                short8 b = *(const short8*)(&Bs[buf][brow * 64 + (((kk * 4 + lg) ^ (lr & 7)) << 3)]);
                acc[jj] = __builtin_amdgcn_mfma_f32_16x16x32_bf16(a, b, acc[jj], 0, 0, 0);
            }
        }
        __syncthreads();
    }
    #undef PSTAGE

    #pragma unroll
    for (int r = 0; r < 4; ++r) {
        int m = m0 + wv * 16 + lg * 4 + r;      // window-order row
        int wi = m / 343, tk = m - wi * 343;
        int ts = tk / 49, rm = tk - ts * 49, th = rm / 7, tw = rm - th * 7;
        int ps = (wi >> 6) * 7 + ts, ph = ((wi >> 3) & 7) * 7 + th, pw = (wi & 7) * 7 + tw;
        int ss_ = ps + 3; if (ss_ >= 14) ss_ -= 14;
        int hh = ph + 3; if (hh >= 56) hh -= 56;
        int ww = pw + 3; if (ww >= 56) ww -= 56;
        size_t l = ((size_t)ss_ * 56 + hh) * 56 + ww;
        float val[12];
        float sum = 0.f, ssum = 0.f;
        #pragma unroll
        for (int jj = 0; jj < 12; ++jj) {
            int col = jj * 16 + lr;
            float v = acc[jj][r] + bias[col] + xt[l * 192 + col];
            xt[l * 192 + col] = v;
            val[jj] = v; sum += v; ssum += v * v;
        }
        #pragma unroll
        for (int off = 1; off < 16; off <<= 1) {
            sum += __shfl_xor(sum, off);
            ssum += __shfl_xor(ssum, off);
        }
        float mu = sum * (1.f / 192.f);
        float rs = rsqrtf(ssum * (1.f / 192.f) - mu * mu + 1e-5f);
        #pragma unroll
        for (int jj = 0; jj < 12; ++jj) {
            int col = jj * 16 + lr;
            h1[l * 192 + col] = f2bf((val[jj] - mu) * rs * g2[col] + b2[col]);
        }
    }
}

// ---------------- flash attention, fixed-max softmax; interior-window fast path ----------------
__global__ __launch_bounds__(256) void attn_flash(
    const unsigned short* __restrict__ qkv, const float* __restrict__ biasC,
    unsigned short* __restrict__ aout) {
    __shared__ unsigned short Ks[352 * 32];     // K rows, chunk-swizzled
    __shared__ unsigned short Vt[32][360];      // V transposed [dim][key]
    __shared__ unsigned int Ps2[4][16][20];     // per-wave P repack scratch
    __shared__ unsigned char regq[352];
    const int w = blockIdx.x, h = blockIdx.y;
    const int tid = threadIdx.x;
    const size_t base = (size_t)w * NTOK * 576;
    // fully-interior window: all shift-mask regions are 0 -> mask is identically 0
    const bool interior = ((w >> 6) == 0) && (((w >> 3) & 7) != 7) && ((w & 7) != 7);

    for (int g = tid; g < 1372; g += 256) {
        int row = g >> 2, c = g & 3;
        gload16(qkv + base + (size_t)row * 576 + 192 + h * 32 + ((c ^ ((row >> 1) & 3)) << 3), Ks + g * 8);
    }
    if (tid < 36) {
        short8 z = {};
        *(short8*)(Ks + (343 + (tid >> 2)) * 32 + (tid & 3) * 8) = z;
    }
    for (int idx = tid; idx < 688; idx += 256) {
        int jp = idx >> 2, c = idx & 3;
        int j0 = jp * 2, j1 = j0 + 1;
        short8 v0 = *(const short8*)(qkv + base + (size_t)j0 * 576 + 384 + h * 32 + c * 8);
        short8 v1 = {};
        if (j1 < NTOK) v1 = *(const short8*)(qkv + base + (size_t)j1 * 576 + 384 + h * 32 + c * 8);
        #pragma unroll
        for (int i = 0; i < 8; ++i) {
            ushort2 pr; pr.x = (unsigned short)v0[i]; pr.y = (unsigned short)v1[i];
            *(ushort2*)&Vt[c * 8 + i][j0] = pr;
        }
    }
    for (int idx = tid; idx < 128; idx += 256) {
        ushort2 z; z.x = 0; z.y = 0;
        *(ushort2*)&Vt[idx >> 2][344 + (idx & 3) * 2] = z;
    }
    if (!interior) {
        const int wis = w >> 6, wih = (w >> 3) & 7, wiw = w & 7;
        for (int n = tid; n < 352; n += 256) {
            unsigned char rv = 0;
            if (n < NTOK) {
                int ts = n / 49, r49 = n - ts * 49, th = r49 / 7, tw = r49 - th * 7;
                int ps = wis * 7 + ts, ph = wih * 7 + th, pw = wiw * 7 + tw;
                int rs = ps < 7 ? 0 : (ps < 11 ? 1 : 2);
                int rh = ph < 49 ? 0 : (ph < 53 ? 1 : 2);
                int rw = pw < 49 ? 0 : (pw < 53 ? 1 : 2);
                rv = (unsigned char)(rs * 9 + rh * 3 + rw);
            }
            regq[n] = rv;
        }
    }
    __syncthreads();

    const int wid = tid >> 6, l = tid & 63, lr = l & 15, lg = l >> 4;
    const int kchunk = (lg ^ ((lr >> 1) & 3)) << 3;   // swizzled Ks read offset

    for (int qt = wid; qt < 22; qt += 4) {
        int qrow = qt * 16 + lr;
        int qr = qrow < NTOK ? qrow : NTOK - 1;
        short8 qa = *(const short8*)(qkv + base + (size_t)qr * 576 + h * 32 + lg * 8);
        const float* bq = biasC + ((size_t)h * NTOK + qr) * BSTRIDE + lg * 4;

        float lsum = 0.f;
        f32x4 o0 = (f32x4){0.f, 0.f, 0.f, 0.f};
        f32x4 o1 = (f32x4){0.f, 0.f, 0.f, 0.f};
        const f32x4 zv = (f32x4){0.f, 0.f, 0.f, 0.f};

        if (interior) {
            #pragma unroll 1
            for (int kb = 0; kb < 11; ++kb) {
                const int kt0 = 2 * kb, kt1 = 2 * kb + 1;
                short8 k0 = *(const short8*)(Ks + (kt0 * 16 + lr) * 32 + kchunk);
                short8 k1 = *(const short8*)(Ks + (kt1 * 16 + lr) * 32 + kchunk);
                f32x4 s0 = __builtin_amdgcn_mfma_f32_16x16x32_bf16(k0, qa, zv, 0, 0, 0);
                f32x4 s1 = __builtin_amdgcn_mfma_f32_16x16x32_bf16(k1, qa, zv, 0, 0, 0);
                f32x4 bv0 = *(const f32x4*)(bq + kt0 * 16);
                f32x4 bv1 = *(const f32x4*)(bq + kt1 * 16);
                f32x4 p0, p1;
                #pragma unroll
                for (int r = 0; r < 4; ++r) {
                    p0[r] = exp2f(s0[r] + bv0[r]);
                    p1[r] = exp2f(s1[r] + bv1[r]);
                    lsum += p0[r] + p1[r];
                }
                Ps2[wid][lr][lg * 2 + 0] = cvtpk(p0[0], p0[1]);
                Ps2[wid][lr][lg * 2 + 1] = cvtpk(p0[2], p0[3]);
                Ps2[wid][lr][8 + lg * 2 + 0] = cvtpk(p1[0], p1[1]);
                Ps2[wid][lr][8 + lg * 2 + 1] = cvtpk(p1[2], p1[3]);
                short8 pa = *(const short8*)&Ps2[wid][lr][lg * 4];
                short8 v0 = *(const short8*)&Vt[lr][kb * 32 + lg * 8];
                short8 v1 = *(const short8*)&Vt[16 + lr][kb * 32 + lg * 8];
                o0 = __builtin_amdgcn_mfma_f32_16x16x32_bf16(pa, v0, o0, 0, 0, 0);
                o1 = __builtin_amdgcn_mfma_f32_16x16x32_bf16(pa, v1, o1, 0, 0, 0);
            }
        } else {
            unsigned int rq = regq[qr];
            #pragma unroll 1
            for (int kb = 0; kb < 11; ++kb) {
                const int kt0 = 2 * kb, kt1 = 2 * kb + 1;
                short8 k0 = *(const short8*)(Ks + (kt0 * 16 + lr) * 32 + kchunk);
                short8 k1 = *(const short8*)(Ks + (kt1 * 16 + lr) * 32 + kchunk);
                f32x4 s0 = __builtin_amdgcn_mfma_f32_16x16x32_bf16(k0, qa, zv, 0, 0, 0);
                f32x4 s1 = __builtin_amdgcn_mfma_f32_16x16x32_bf16(k1, qa, zv, 0, 0, 0);
                f32x4 bv0 = *(const f32x4*)(bq + kt0 * 16);
                f32x4 bv1 = *(const f32x4*)(bq + kt1 * 16);
                unsigned int rb0 = *(const unsigned int*)&regq[kt0 * 16 + lg * 4];
                unsigned int rb1 = *(const unsigned int*)&regq[kt1 * 16 + lg * 4];
                f32x4 p0, p1;
                #pragma unroll
                for (int r = 0; r < 4; ++r) {
                    float m0 = (((rb0 >> (r * 8)) & 255u) != rq) ? NMASK : 0.f;
                    float m1 = (((rb1 >> (r * 8)) & 255u) != rq) ? NMASK : 0.f;
                    p0[r] = exp2f(s0[r] + bv0[r] + m0);
                    p1[r] = exp2f(s1[r] + bv1[r] + m1);
                    lsum += p0[r] + p1[r];
                }
                Ps2[wid][lr][lg * 2 + 0] = cvtpk(p0[0], p0[1]);
                Ps2[wid][lr][lg * 2 + 1] = cvtpk(p0[2], p0[3]);
                Ps2[wid][lr][8 + lg * 2 + 0] = cvtpk(p1[0], p1[1]);
                Ps2[wid][lr][8 + lg * 2 + 1] = cvtpk(p1[2], p1[3]);
                short8 pa = *(const short8*)&Ps2[wid][lr][lg * 4];
                short8 v0 = *(const short8*)&Vt[lr][kb * 32 + lg * 8];
                short8 v1 = *(const short8*)&Vt[16 + lr][kb * 32 + lg * 8];
                o0 = __builtin_amdgcn_mfma_f32_16x16x32_bf16(pa, v0, o0, 0, 0, 0);
                o1 = __builtin_amdgcn_mfma_f32_16x16x32_bf16(pa, v1, o1, 0, 0, 0);
            }
        }
        lsum += __shfl_xor(lsum, 16);
        lsum += __shfl_xor(lsum, 32);
        float inv = 1.f / lsum;

        #pragma unroll
        for (int r = 0; r < 4; ++r) {
            float iv = __shfl(inv, lg * 4 + r);
            int q = qt * 16 + lg * 4 + r;
            if (q < NTOK) {
                size_t orow = ((size_t)w * NTOK + q) * 192 + h * 32;
                aout[orow + lr] = f2bf(o0[r] * iv);
                aout[orow + 16 + lr] = f2bf(o1[r] * iv);
            }
        }
    }
}

extern "C" void kernel_launch(void* const* d_in, const int* in_sizes, int n_in,
                              void* d_out, int out_size, void* d_ws, size_t ws_size,
                              hipStream_t stream) {
    const float* x      = (const float*)d_in[0];
    const float* n1g    = (const float*)d_in[1];
    const float* n1b    = (const float*)d_in[2];
    const float* qkv_w  = (const float*)d_in[3];
    const float* qkv_b  = (const float*)d_in[4];
    const float* rpb    = (const float*)d_in[5];
    const float* proj_w = (const float*)d_in[6];
    const float* proj_b = (const float*)d_in[7];
    const float* n2g    = (const float*)d_in[8];
    const float* n2b    = (const float*)d_in[9];
    const float* fc1_w  = (const float*)d_in[10];
    const float* fc1_b  = (const float*)d_in[11];
    const float* fc2_w  = (const float*)d_in[12];
    const float* fc2_b  = (const float*)d_in[13];
    float* out = (float*)d_out;

    // workspace layout (h2 overlays qkvb [L][768])
    char* p = (char*)d_ws;
    float* xt = (float*)p;                     p += (size_t)L_TOK * 192 * 4;   // residual f32
    unsigned short* xw = (unsigned short*)p;   // LN1 out bf16; later h1 (LN2 out bf16)
    unsigned short* h1 = xw;                   p += (size_t)L_TOK * 192 * 2;
    unsigned short* qkvb = (unsigned short*)p; // qkv bf16 [L][576]; later h2 [L][768]
    unsigned short* h2 = qkvb;                 p += (size_t)L_TOK * 768 * 2;
    unsigned short* aoutb = (unsigned short*)p; p += (size_t)L_TOK * 192 * 2;  // attn out bf16
    float* biasC = (float*)p;                  p += (size_t)NHEAD * NTOK * BSTRIDE * 4 + 256;
    unsigned short* qkvT = (unsigned short*)p; p += (size_t)576 * 192 * 2;
    unsigned short* projT = (unsigned short*)p; p += (size_t)192 * 192 * 2;
    unsigned short* fc1T = (unsigned short*)p; p += (size_t)768 * 192 * 2;
    unsigned short* fc2T = (unsigned short*)p; p += (size_t)192 * 768 * 2;
    float* qkvb_s = (float*)p;                 p += 576 * 4;

    prep_kernel<<<919, 256, 0, stream>>>(qkv_w, qkv_b, proj_w, fc1_w, fc2_w, rpb,
                                         qkvT, projT, fc1T, fc2T, qkvb_s, biasC);
    ln1_part<<<686, 256, 0, stream>>>(x, n1g, n1b, xt, xw);
    // QKV: (L,192)@(192,576) -> bf16 (q pre-scaled). Grid (n, m) for A-panel L2 reuse.
    gemm_bf16<0, 0><<<dim3(9, 343), 256, 0, stream>>>(xw, qkvT, qkvb_s, qkvb, nullptr, 576, 192);
    // attention -> aoutb bf16
    attn_flash<<<dim3(NWIN, NHEAD), 256, 0, stream>>>(qkvb, biasC, aoutb);
    // fused proj + window-reverse residual (xt inout) + LN2 -> h1 bf16
    gemm_proj_ln<<<686, 256, 0, stream>>>(aoutb, projT, proj_b, n2g, n2b, xt, h1);
    // fc1+GELU: (L,192)@(192,768) -> bf16
    gemm_bf16<1, 0><<<dim3(12, 343), 256, 0, stream>>>(h1, fc1T, fc1_b, h2, nullptr, 768, 192);
    // fc2: (L,768)@(768,192) + xt residual, transposed write to out (C,L)
    gemm_bf16<0, 2><<<dim3(3, 343), 256, 0, stream>>>(h2, fc2T, fc2_b, out, xt, 192, 768);
}

// Round 15
// 220.953 us; speedup vs baseline: 1.8375x; 1.0125x over previous
//
#include <hip/hip_runtime.h>
#include <hip/hip_bf16.h>
#include <math.h>

#define L_TOK 43904          // 14*56*56 tokens
#define NWIN 128
#define NTOK 343
#define NHEAD 6
#define SCALE 0.17677669529663687f
#define LOG2E 1.4426950408889634f
#define NMASK -144.26950408889634f   // -100 * log2(e)
#define BSTRIDE 352                  // bias row stride (k padded, pad = -30000)
#define FIXMAX 16.0f                 // fixed softmax max (folded into biasC)

typedef __attribute__((ext_vector_type(8))) short short8;
typedef __attribute__((ext_vector_type(4))) float f32x4;

__device__ __forceinline__ unsigned short f2bf(float x) {
    union { float f; unsigned int u; } v; v.f = x;
    unsigned int r = v.u + 0x7fffu + ((v.u >> 16) & 1u);
    return (unsigned short)(r >> 16);
}
__device__ __forceinline__ unsigned int cvtpk(float a, float b) {
    unsigned int r;
    asm volatile("v_cvt_pk_bf16_f32 %0, %1, %2" : "=v"(r) : "v"(a), "v"(b));
    return r;
}
__device__ __forceinline__ void gload16(const void* g, void* l) {
    __builtin_amdgcn_global_load_lds((const __attribute__((address_space(1))) void*)g,
                                     (__attribute__((address_space(3))) void*)l, 16, 0, 0);
}

// map spatial token index l -> window-order row (roll -3 fused)
__device__ __forceinline__ int winrow(int l) {
    int s = l / 3136;
    int rem = l - s * 3136;
    int h = rem / 56;
    int w = rem - h * 56;
    int ps = s + 11; if (ps >= 14) ps -= 14;
    int ph = h + 53; if (ph >= 56) ph -= 56;
    int pw = w + 53; if (pw >= 56) pw -= 56;
    int wi = ((ps / 7) * 8 + ph / 7) * 8 + pw / 7;
    int tk = ((ps % 7) * 7 + ph % 7) * 7 + pw % 7;
    return wi * NTOK + tk;
}

// ---------------- merged prep: weight conversion (blocks 0..575) + bias table (blocks 576..918) ----------------
__global__ __launch_bounds__(256) void prep_kernel(
    const float* __restrict__ qkv_w, const float* __restrict__ qkv_b,
    const float* __restrict__ proj_w, const float* __restrict__ fc1_w,
    const float* __restrict__ fc2_w, const float* __restrict__ table,
    unsigned short* __restrict__ qkvT, unsigned short* __restrict__ projT,
    unsigned short* __restrict__ fc1T, unsigned short* __restrict__ fc2T,
    float* __restrict__ qkvb_s, float* __restrict__ biasC) {
    const float qs = SCALE * LOG2E;
    if (blockIdx.x < 576) {
        int stride = 576 * 256;
        int t0 = blockIdx.x * 256 + threadIdx.x;
        for (int i = t0; i < 576 * 192; i += stride) {
            int n = i / 192, k = i - n * 192;
            float v = qkv_w[k * 576 + n];
            if (n < 192) v *= qs;
            qkvT[i] = f2bf(v);
        }
        for (int i = t0; i < 192 * 192; i += stride) {
            int n = i / 192, k = i - n * 192;
            projT[i] = f2bf(proj_w[k * 192 + n]);
        }
        for (int i = t0; i < 768 * 192; i += stride) {
            int n = i / 192, k = i - n * 192;
            fc1T[i] = f2bf(fc1_w[k * 768 + n]);
        }
        for (int i = t0; i < 192 * 768; i += stride) {
            int n = i / 768, k = i - n * 768;
            fc2T[i] = f2bf(fc2_w[k * 192 + n]);
        }
        for (int i = t0; i < 576; i += stride) {
            float v = qkv_b[i]; if (i < 192) v *= qs;
            qkvb_s[i] = v;
        }
    } else {
        int q = blockIdx.x - 576;      // 0..342
        int qs3 = q / 49, qh = (q / 7) % 7, qw = q % 7;
        for (int k = threadIdx.x; k < BSTRIDE; k += 256) {
            if (k < NTOK) {
                int ks = k / 49, kh = (k / 7) % 7, kw = k % 7;
                int idx = ((qs3 - ks + 6) * 13 + (qh - kh + 6)) * 13 + (qw - kw + 6);
                #pragma unroll
                for (int h = 0; h < NHEAD; ++h)
                    biasC[((size_t)h * NTOK + q) * BSTRIDE + k] = table[idx * 6 + h] * LOG2E - FIXMAX;
            } else {
                #pragma unroll
                for (int h = 0; h < NHEAD; ++h)
                    biasC[((size_t)h * NTOK + q) * BSTRIDE + k] = -30000.f;
            }
        }
    }
}

// ---------------- K1: transpose to (L,C) + LN1 + shifted window partition (bf16 out) ----------------
__global__ __launch_bounds__(256) void ln1_part(const float* __restrict__ x,
                                                const float* __restrict__ g, const float* __restrict__ b,
                                                float* __restrict__ xt, unsigned short* __restrict__ xw) {
    __shared__ float tile[192 * 65];
    __shared__ float red[4][64];
    __shared__ float red2[4][64];
    __shared__ float mu_s[64], rs_s[64];
    int l0 = blockIdx.x * 64;
    int tid = threadIdx.x;
    int j = tid & 63, c4 = tid >> 6;
    for (int cb = 0; cb < 192; cb += 4)
        tile[(cb + c4) * 65 + j] = x[(size_t)(cb + c4) * L_TOK + l0 + j];
    __syncthreads();
    float s = 0.f, ss = 0.f;
    for (int c = c4 * 48; c < c4 * 48 + 48; ++c) {
        float v = tile[c * 65 + j];
        s += v; ss += v * v;
    }
    red[c4][j] = s; red2[c4][j] = ss;
    __syncthreads();
    if (tid < 64) {
        float S = red[0][j] + red[1][j] + red[2][j] + red[3][j];
        float SS = red2[0][j] + red2[1][j] + red2[2][j] + red2[3][j];
        float mu = S * (1.f / 192.f);
        float var = SS * (1.f / 192.f) - mu * mu;
        mu_s[j] = mu;
        rs_s[j] = rsqrtf(var + 1e-5f);
    }
    __syncthreads();
    int wave = tid >> 6, lid = tid & 63;
    for (int t = wave; t < 64; t += 4) {
        int l = l0 + t;
        int r = winrow(l);
        float mu = mu_s[t], rs = rs_s[t];
        #pragma unroll
        for (int q = 0; q < 3; ++q) {
            int c = q * 64 + lid;
            float v = tile[c * 65 + t];
            xt[(size_t)l * 192 + c] = v;
            xw[(size_t)r * 192 + c] = f2bf((v - mu) * rs * g[c] + b[c]);
        }
    }
}

// ---------------- bf16 MFMA GEMM: C[M,N]=A[M,K]@Bt[N,K]^T + bias ----------------
// BM=128 BN=64 BK=64. Grid: (x = n-block, y = m-block) so consecutive blocks share the A panel (L2 reuse).
// EPI=1: exact GELU. OUTMODE: 0=bf16, 1=f32, 2=f32 transposed out[(n0+c)*L+m] with xt-residual add.
template<int EPI, int OUTMODE>
__global__ __launch_bounds__(256, 3) void gemm_bf16(
    const unsigned short* __restrict__ A, const unsigned short* __restrict__ Bt,
    const float* __restrict__ bias, void* __restrict__ Cout,
    const float* __restrict__ xt, int N, int K) {
    __shared__ unsigned char smem[49152];
    unsigned short* sh = (unsigned short*)smem;
    const int tid = threadIdx.x;
    const int m0 = blockIdx.y * 128;
    const int n0 = blockIdx.x * 64;
    const int lane = tid & 63, wv = tid >> 6;
    const int wm = wv >> 1, wn = wv & 1;
    const int lr = lane & 15, lg = lane >> 4;
    const int KT = K >> 6;

    f32x4 acc[4][2];
    #pragma unroll
    for (int i = 0; i < 4; ++i)
        #pragma unroll
        for (int jj = 0; jj < 2; ++jj)
            acc[i][jj] = (f32x4){0.f, 0.f, 0.f, 0.f};

    #define STAGE(BUF, K0) { \
        unsigned short* dst = sh + (BUF) * 12288; \
        _Pragma("unroll") \
        for (int i_ = 0; i_ < 4; ++i_) { \
            int g_ = (i_ * 4 + wv) * 64 + lane; \
            int row_ = g_ >> 3, gc_ = g_ & 7; \
            gload16(A + (size_t)(m0 + row_) * K + (K0) + ((gc_ ^ (row_ & 7)) << 3), dst + g_ * 8); \
        } \
        _Pragma("unroll") \
        for (int i_ = 0; i_ < 2; ++i_) { \
            int g_ = (i_ * 4 + wv) * 64 + lane; \
            int row_ = g_ >> 3, gc_ = g_ & 7; \
            gload16(Bt + (size_t)(n0 + row_) * K + (K0) + ((gc_ ^ (row_ & 7)) << 3), dst + 8192 + g_ * 8); \
        } }

    STAGE(0, 0);
    __syncthreads();
    for (int kt = 0; kt < KT; ++kt) {
        int buf = kt & 1;
        if (kt + 1 < KT) STAGE(buf ^ 1, (kt + 1) << 6);
        const unsigned short* sA = sh + buf * 12288;
        const unsigned short* sB = sA + 8192;
        #pragma unroll
        for (int kk = 0; kk < 2; ++kk) {
            short8 a[4], b[2];
            #pragma unroll
            for (int i = 0; i < 4; ++i) {
                int row = wm * 64 + i * 16 + lr;
                a[i] = *(const short8*)(sA + row * 64 + (((kk * 4 + lg) ^ (lr & 7)) << 3));
            }
            #pragma unroll
            for (int jj = 0; jj < 2; ++jj) {
                int row = wn * 32 + jj * 16 + lr;
                b[jj] = *(const short8*)(sB + row * 64 + (((kk * 4 + lg) ^ (lr & 7)) << 3));
            }
            #pragma unroll
            for (int i = 0; i < 4; ++i)
                #pragma unroll
                for (int jj = 0; jj < 2; ++jj)
                    acc[i][jj] = __builtin_amdgcn_mfma_f32_16x16x32_bf16(a[i], b[jj], acc[i][jj], 0, 0, 0);
        }
        __syncthreads();
    }
    #undef STAGE

    if (OUTMODE == 2) {
        float* Cs = (float*)smem;   // [128][68]
        #pragma unroll
        for (int i = 0; i < 4; ++i)
            #pragma unroll
            for (int jj = 0; jj < 2; ++jj)
                #pragma unroll
                for (int r = 0; r < 4; ++r) {
                    int row = wm * 64 + i * 16 + lg * 4 + r;
                    int col = wn * 32 + jj * 16 + lr;
                    float v = acc[i][jj][r] + bias[n0 + col] + xt[(size_t)(m0 + row) * 192 + n0 + col];
                    Cs[row * 68 + col] = v;
                }
        __syncthreads();
        float* outp = (float*)Cout;
        int c = tid & 63;
        #pragma unroll
        for (int j4 = tid >> 6; j4 < 32; j4 += 4) {
            f32x4 v;
            #pragma unroll
            for (int t = 0; t < 4; ++t) v[t] = Cs[(j4 * 4 + t) * 68 + c];
            *(f32x4*)&outp[(size_t)(n0 + c) * L_TOK + m0 + j4 * 4] = v;
        }
    } else {
        float bia[2];
        bia[0] = bias[n0 + wn * 32 + lr];
        bia[1] = bias[n0 + wn * 32 + 16 + lr];
        #pragma unroll
        for (int i = 0; i < 4; ++i) {
            #pragma unroll
            for (int jj = 0; jj < 2; ++jj) {
                #pragma unroll
                for (int r = 0; r < 4; ++r) {
                    float v = acc[i][jj][r] + bia[jj];
                    if (EPI == 1) v = 0.5f * v * (1.f + erff(v * 0.70710678118654752f));
                    int row = m0 + wm * 64 + i * 16 + lg * 4 + r;
                    int col = n0 + wn * 32 + jj * 16 + lr;
                    if (OUTMODE == 1) ((float*)Cout)[(size_t)row * N + col] = v;
                    else ((unsigned short*)Cout)[(size_t)row * N + col] = f2bf(v);
                }
            }
        }
    }
}

// ---------------- fused proj GEMM + window-reverse residual + LN2 ----------------
__global__ __launch_bounds__(256) void gemm_proj_ln(
    const unsigned short* __restrict__ A, const unsigned short* __restrict__ Bt,
    const float* __restrict__ bias, const float* __restrict__ g2, const float* __restrict__ b2,
    float* __restrict__ xt, unsigned short* __restrict__ h1) {
    __shared__ unsigned short As[2][64 * 64];
    __shared__ unsigned short Bs[2][192 * 64];
    const int tid = threadIdx.x;
    const int m0 = blockIdx.x * 64;
    const int lane = tid & 63, wv = tid >> 6;
    const int lr = lane & 15, lg = lane >> 4;
    const int K = 192;

    f32x4 acc[12];
    #pragma unroll
    for (int jj = 0; jj < 12; ++jj) acc[jj] = (f32x4){0.f, 0.f, 0.f, 0.f};

    #define PSTAGE(BUF, K0) { \
        _Pragma("unroll") \
        for (int i_ = 0; i_ < 2; ++i_) { \
            int g_ = i_ * 256 + tid; \
            int row_ = g_ >> 3, gc_ = g_ & 7; \
            gload16(A + (size_t)(m0 + row_) * K + (K0) + ((gc_ ^ (row_ & 7)) << 3), &As[BUF][g_ * 8]); \
        } \
        _Pragma("unroll") \
        for (int i_ = 0; i_ < 6; ++i_) { \
            int g_ = i_ * 256 + tid; \
            int row_ = g_ >> 3, gc_ = g_ & 7; \
            gload16(Bt + (size_t)row_ * K + (K0) + ((gc_ ^ (row_ & 7)) << 3), &Bs[BUF][g_ * 8]); \
        } }

    PSTAGE(0, 0);
    __syncthreads();
    for (int kt = 0; kt < 3; ++kt) {
        int buf = kt & 1;
        if (kt + 1 < 3) PSTAGE(buf ^ 1, (kt + 1) << 6);
        #pragma unroll
        for (int kk = 0; kk < 2; ++kk) {
            int arow = wv * 16 + lr;
            short8 a = *(const short8*)(&As[buf][arow * 64 + (((kk * 4 + lg) ^ (lr & 7)) << 3)]);
            #pragma unroll
            for (int jj = 0; jj < 12; ++jj) {
                int brow = jj * 16 + lr;
                short8 b = *(const short8*)(&Bs[buf][brow * 64 + (((kk * 4 + lg) ^ (lr & 7)) << 3)]);
                acc[jj] = __builtin_amdgcn_mfma_f32_16x16x32_bf16(a, b, acc[jj], 0, 0, 0);
            }
        }
        __syncthreads();
    }
    #undef PSTAGE

    #pragma unroll
    for (int r = 0; r < 4; ++r) {
        int m = m0 + wv * 16 + lg * 4 + r;      // window-order row
        int wi = m / 343, tk = m - wi * 343;
        int ts = tk / 49, rm = tk - ts * 49, th = rm / 7, tw = rm - th * 7;
        int ps = (wi >> 6) * 7 + ts, ph = ((wi >> 3) & 7) * 7 + th, pw = (wi & 7) * 7 + tw;
        int ss_ = ps + 3; if (ss_ >= 14) ss_ -= 14;
        int hh = ph + 3; if (hh >= 56) hh -= 56;
        int ww = pw + 3; if (ww >= 56) ww -= 56;
        size_t l = ((size_t)ss_ * 56 + hh) * 56 + ww;
        float val[12];
        float sum = 0.f, ssum = 0.f;
        #pragma unroll
        for (int jj = 0; jj < 12; ++jj) {
            int col = jj * 16 + lr;
            float v = acc[jj][r] + bias[col] + xt[l * 192 + col];
            xt[l * 192 + col] = v;
            val[jj] = v; sum += v; ssum += v * v;
        }
        #pragma unroll
        for (int off = 1; off < 16; off <<= 1) {
            sum += __shfl_xor(sum, off);
            ssum += __shfl_xor(ssum, off);
        }
        float mu = sum * (1.f / 192.f);
        float rs = rsqrtf(ssum * (1.f / 192.f) - mu * mu + 1e-5f);
        #pragma unroll
        for (int jj = 0; jj < 12; ++jj) {
            int col = jj * 16 + lr;
            h1[l * 192 + col] = f2bf((val[jj] - mu) * rs * g2[col] + b2[col]);
        }
    }
}

// ---------------- flash attention, fixed-max softmax; kb-unroll-2 ILP + setprio ----------------
__global__ __launch_bounds__(256) void attn_flash(
    const unsigned short* __restrict__ qkv, const float* __restrict__ biasC,
    unsigned short* __restrict__ aout) {
    __shared__ unsigned short Ks[352 * 32];     // K rows, chunk-swizzled
    __shared__ unsigned short Vt[32][360];      // V transposed [dim][key]
    __shared__ unsigned int Ps2[4][16][20];     // per-wave P repack scratch
    __shared__ unsigned char regq[352];
    const int w = blockIdx.x, h = blockIdx.y;
    const int tid = threadIdx.x;
    const size_t base = (size_t)w * NTOK * 576;
    const bool interior = ((w >> 6) == 0) && (((w >> 3) & 7) != 7) && ((w & 7) != 7);

    for (int g = tid; g < 1372; g += 256) {
        int row = g >> 2, c = g & 3;
        gload16(qkv + base + (size_t)row * 576 + 192 + h * 32 + ((c ^ ((row >> 1) & 3)) << 3), Ks + g * 8);
    }
    if (tid < 36) {
        short8 z = {};
        *(short8*)(Ks + (343 + (tid >> 2)) * 32 + (tid & 3) * 8) = z;
    }
    for (int idx = tid; idx < 688; idx += 256) {
        int jp = idx >> 2, c = idx & 3;
        int j0 = jp * 2, j1 = j0 + 1;
        short8 v0 = *(const short8*)(qkv + base + (size_t)j0 * 576 + 384 + h * 32 + c * 8);
        short8 v1 = {};
        if (j1 < NTOK) v1 = *(const short8*)(qkv + base + (size_t)j1 * 576 + 384 + h * 32 + c * 8);
        #pragma unroll
        for (int i = 0; i < 8; ++i) {
            ushort2 pr; pr.x = (unsigned short)v0[i]; pr.y = (unsigned short)v1[i];
            *(ushort2*)&Vt[c * 8 + i][j0] = pr;
        }
    }
    for (int idx = tid; idx < 128; idx += 256) {
        ushort2 z; z.x = 0; z.y = 0;
        *(ushort2*)&Vt[idx >> 2][344 + (idx & 3) * 2] = z;
    }
    if (!interior) {
        const int wis = w >> 6, wih = (w >> 3) & 7, wiw = w & 7;
        for (int n = tid; n < 352; n += 256) {
            unsigned char rv = 0;
            if (n < NTOK) {
                int ts = n / 49, r49 = n - ts * 49, th = r49 / 7, tw = r49 - th * 7;
                int ps = wis * 7 + ts, ph = wih * 7 + th, pw = wiw * 7 + tw;
                int rs = ps < 7 ? 0 : (ps < 11 ? 1 : 2);
                int rh = ph < 49 ? 0 : (ph < 53 ? 1 : 2);
                int rw = pw < 49 ? 0 : (pw < 53 ? 1 : 2);
                rv = (unsigned char)(rs * 9 + rh * 3 + rw);
            }
            regq[n] = rv;
        }
    }
    __syncthreads();

    const int wid = tid >> 6, l = tid & 63, lr = l & 15, lg = l >> 4;
    const int kchunk = (lg ^ ((lr >> 1) & 3)) << 3;   // swizzled Ks read offset

    for (int qt = wid; qt < 22; qt += 4) {
        int qrow = qt * 16 + lr;
        int qr = qrow < NTOK ? qrow : NTOK - 1;
        short8 qa = *(const short8*)(qkv + base + (size_t)qr * 576 + h * 32 + lg * 8);
        const float* bq = biasC + ((size_t)h * NTOK + qr) * BSTRIDE + lg * 4;

        float lsum = 0.f;
        f32x4 o0 = (f32x4){0.f, 0.f, 0.f, 0.f};
        f32x4 o1 = (f32x4){0.f, 0.f, 0.f, 0.f};
        const f32x4 zv = (f32x4){0.f, 0.f, 0.f, 0.f};

        if (interior) {
            #pragma unroll 2
            for (int kb = 0; kb < 11; ++kb) {
                const int kt0 = 2 * kb, kt1 = 2 * kb + 1;
                short8 k0 = *(const short8*)(Ks + (kt0 * 16 + lr) * 32 + kchunk);
                short8 k1 = *(const short8*)(Ks + (kt1 * 16 + lr) * 32 + kchunk);
                __builtin_amdgcn_s_setprio(1);
                f32x4 s0 = __builtin_amdgcn_mfma_f32_16x16x32_bf16(k0, qa, zv, 0, 0, 0);
                f32x4 s1 = __builtin_amdgcn_mfma_f32_16x16x32_bf16(k1, qa, zv, 0, 0, 0);
                __builtin_amdgcn_s_setprio(0);
                f32x4 bv0 = *(const f32x4*)(bq + kt0 * 16);
                f32x4 bv1 = *(const f32x4*)(bq + kt1 * 16);
                f32x4 p0, p1;
                #pragma unroll
                for (int r = 0; r < 4; ++r) {
                    p0[r] = exp2f(s0[r] + bv0[r]);
                    p1[r] = exp2f(s1[r] + bv1[r]);
                    lsum += p0[r] + p1[r];
                }
                Ps2[wid][lr][lg * 2 + 0] = cvtpk(p0[0], p0[1]);
                Ps2[wid][lr][lg * 2 + 1] = cvtpk(p0[2], p0[3]);
                Ps2[wid][lr][8 + lg * 2 + 0] = cvtpk(p1[0], p1[1]);
                Ps2[wid][lr][8 + lg * 2 + 1] = cvtpk(p1[2], p1[3]);
                short8 pa = *(const short8*)&Ps2[wid][lr][lg * 4];
                short8 v0 = *(const short8*)&Vt[lr][kb * 32 + lg * 8];
                short8 v1 = *(const short8*)&Vt[16 + lr][kb * 32 + lg * 8];
                __builtin_amdgcn_s_setprio(1);
                o0 = __builtin_amdgcn_mfma_f32_16x16x32_bf16(pa, v0, o0, 0, 0, 0);
                o1 = __builtin_amdgcn_mfma_f32_16x16x32_bf16(pa, v1, o1, 0, 0, 0);
                __builtin_amdgcn_s_setprio(0);
            }
        } else {
            unsigned int rq = regq[qr];
            #pragma unroll 2
            for (int kb = 0; kb < 11; ++kb) {
                const int kt0 = 2 * kb, kt1 = 2 * kb + 1;
                short8 k0 = *(const short8*)(Ks + (kt0 * 16 + lr) * 32 + kchunk);
                short8 k1 = *(const short8*)(Ks + (kt1 * 16 + lr) * 32 + kchunk);
                __builtin_amdgcn_s_setprio(1);
                f32x4 s0 = __builtin_amdgcn_mfma_f32_16x16x32_bf16(k0, qa, zv, 0, 0, 0);
                f32x4 s1 = __builtin_amdgcn_mfma_f32_16x16x32_bf16(k1, qa, zv, 0, 0, 0);
                __builtin_amdgcn_s_setprio(0);
                f32x4 bv0 = *(const f32x4*)(bq + kt0 * 16);
                f32x4 bv1 = *(const f32x4*)(bq + kt1 * 16);
                unsigned int rb0 = *(const unsigned int*)&regq[kt0 * 16 + lg * 4];
                unsigned int rb1 = *(const unsigned int*)&regq[kt1 * 16 + lg * 4];
                f32x4 p0, p1;
                #pragma unroll
                for (int r = 0; r < 4; ++r) {
                    float m0 = (((rb0 >> (r * 8)) & 255u) != rq) ? NMASK : 0.f;
                    float m1 = (((rb1 >> (r * 8)) & 255u) != rq) ? NMASK : 0.f;
                    p0[r] = exp2f(s0[r] + bv0[r] + m0);
                    p1[r] = exp2f(s1[r] + bv1[r] + m1);
                    lsum += p0[r] + p1[r];
                }
                Ps2[wid][lr][lg * 2 + 0] = cvtpk(p0[0], p0[1]);
                Ps2[wid][lr][lg * 2 + 1] = cvtpk(p0[2], p0[3]);
                Ps2[wid][lr][8 + lg * 2 + 0] = cvtpk(p1[0], p1[1]);
                Ps2[wid][lr][8 + lg * 2 + 1] = cvtpk(p1[2], p1[3]);
                short8 pa = *(const short8*)&Ps2[wid][lr][lg * 4];
                short8 v0 = *(const short8*)&Vt[lr][kb * 32 + lg * 8];
                short8 v1 = *(const short8*)&Vt[16 + lr][kb * 32 + lg * 8];
                __builtin_amdgcn_s_setprio(1);
                o0 = __builtin_amdgcn_mfma_f32_16x16x32_bf16(pa, v0, o0, 0, 0, 0);
                o1 = __builtin_amdgcn_mfma_f32_16x16x32_bf16(pa, v1, o1, 0, 0, 0);
                __builtin_amdgcn_s_setprio(0);
            }
        }
        lsum += __shfl_xor(lsum, 16);
        lsum += __shfl_xor(lsum, 32);
        float inv = 1.f / lsum;

        #pragma unroll
        for (int r = 0; r < 4; ++r) {
            float iv = __shfl(inv, lg * 4 + r);
            int q = qt * 16 + lg * 4 + r;
            if (q < NTOK) {
                size_t orow = ((size_t)w * NTOK + q) * 192 + h * 32;
                aout[orow + lr] = f2bf(o0[r] * iv);
                aout[orow + 16 + lr] = f2bf(o1[r] * iv);
            }
        }
    }
}

extern "C" void kernel_launch(void* const* d_in, const int* in_sizes, int n_in,
                              void* d_out, int out_size, void* d_ws, size_t ws_size,
                              hipStream_t stream) {
    const float* x      = (const float*)d_in[0];
    const float* n1g    = (const float*)d_in[1];
    const float* n1b    = (const float*)d_in[2];
    const float* qkv_w  = (const float*)d_in[3];
    const float* qkv_b  = (const float*)d_in[4];
    const float* rpb    = (const float*)d_in[5];
    const float* proj_w = (const float*)d_in[6];
    const float* proj_b = (const float*)d_in[7];
    const float* n2g    = (const float*)d_in[8];
    const float* n2b    = (const float*)d_in[9];
    const float* fc1_w  = (const float*)d_in[10];
    const float* fc1_b  = (const float*)d_in[11];
    const float* fc2_w  = (const float*)d_in[12];
    const float* fc2_b  = (const float*)d_in[13];
    float* out = (float*)d_out;

    // workspace layout (h2 overlays qkvb [L][768])
    char* p = (char*)d_ws;
    float* xt = (float*)p;                     p += (size_t)L_TOK * 192 * 4;   // residual f32
    unsigned short* xw = (unsigned short*)p;   // LN1 out bf16; later h1 (LN2 out bf16)
    unsigned short* h1 = xw;                   p += (size_t)L_TOK * 192 * 2;
    unsigned short* qkvb = (unsigned short*)p; // qkv bf16 [L][576]; later h2 [L][768]
    unsigned short* h2 = qkvb;                 p += (size_t)L_TOK * 768 * 2;
    unsigned short* aoutb = (unsigned short*)p; p += (size_t)L_TOK * 192 * 2;  // attn out bf16
    float* biasC = (float*)p;                  p += (size_t)NHEAD * NTOK * BSTRIDE * 4 + 256;
    unsigned short* qkvT = (unsigned short*)p; p += (size_t)576 * 192 * 2;
    unsigned short* projT = (unsigned short*)p; p += (size_t)192 * 192 * 2;
    unsigned short* fc1T = (unsigned short*)p; p += (size_t)768 * 192 * 2;
    unsigned short* fc2T = (unsigned short*)p; p += (size_t)192 * 768 * 2;
    float* qkvb_s = (float*)p;                 p += 576 * 4;

    prep_kernel<<<919, 256, 0, stream>>>(qkv_w, qkv_b, proj_w, fc1_w, fc2_w, rpb,
                                         qkvT, projT, fc1T, fc2T, qkvb_s, biasC);
    ln1_part<<<686, 256, 0, stream>>>(x, n1g, n1b, xt, xw);
    // QKV: (L,192)@(192,576) -> bf16 (q pre-scaled). Grid (n, m) for A-panel L2 reuse.
    gemm_bf16<0, 0><<<dim3(9, 343), 256, 0, stream>>>(xw, qkvT, qkvb_s, qkvb, nullptr, 576, 192);
    // attention -> aoutb bf16
    attn_flash<<<dim3(NWIN, NHEAD), 256, 0, stream>>>(qkvb, biasC, aoutb);
    // fused proj + window-reverse residual (xt inout) + LN2 -> h1 bf16
    gemm_proj_ln<<<686, 256, 0, stream>>>(aoutb, projT, proj_b, n2g, n2b, xt, h1);
    // fc1+GELU: (L,192)@(192,768) -> bf16
    gemm_bf16<1, 0><<<dim3(12, 343), 256, 0, stream>>>(h1, fc1T, fc1_b, h2, nullptr, 768, 192);
    // fc2: (L,768)@(768,192) + xt residual, transposed write to out (C,L)
    gemm_bf16<0, 2><<<dim3(3, 343), 256, 0, stream>>>(h2, fc2T, fc2_b, out, xt, 192, 768);
}